// Round 6
// baseline (424.703 us; speedup 1.0000x reference)
//
#include <hip/hip_runtime.h>

#define BROWS 65536
#define DDIM 256
#define MCODES 1024
#define EPS_MARGIN 1e-5f
#define RGRP 8
#define NPART 512

typedef __attribute__((ext_vector_type(8))) short short8;   // bf16x8 MFMA frag
typedef __attribute__((ext_vector_type(4))) float float4v;  // fp32x4 acc

__device__ inline unsigned short f2bf_rne(float f) {
  unsigned u = __float_as_uint(f);
  unsigned r = u + 0x7FFFu + ((u >> 16) & 1u);
  return (unsigned short)(r >> 16);
}

__device__ inline short8 as_s8(uint4 v) {
  union { uint4 u; short8 s; } x; x.u = v; return x.s;
}

// ---------------- Kernel 1: numpy-exact pairwise row norms + zero-init (validated) ----------------
__global__ __launch_bounds__(256)
void norms_init_kernel(const float* __restrict__ x, const float* __restrict__ emb,
                       float* __restrict__ xnorm, float* __restrict__ enorm,
                       float* __restrict__ counts, int* __restrict__ nflag,
                       float* __restrict__ loss_extra) {
  int t = blockIdx.x * 256 + threadIdx.x;
  if (t < MCODES) counts[t] = 0.0f;
  if (t == 0) *nflag = 0;
  if (t < 2) loss_extra[t] = 0.0f;
  int row = t >> 4;
  int lane = t & 15;
  const float* p;
  float* dst;
  int r;
  if (row < BROWS) { p = x + (size_t)row * DDIM; dst = xnorm; r = row; }
  else             { p = emb + (size_t)(row - BROWS) * DDIM; dst = enorm; r = row - BROWS; }
  int half = (lane >> 3) & 1;
  int j = lane & 7;
  const float* q = p + half * 128 + j;
  float v = q[0];
  float acc = __fmul_rn(v, v);
  #pragma unroll
  for (int i = 1; i < 16; ++i) {
    v = q[i * 8];
    acc = __fadd_rn(acc, __fmul_rn(v, v));
  }
  float o;
  o = __shfl_xor(acc, 1, 64); acc = __fadd_rn(acc, o);
  o = __shfl_xor(acc, 2, 64); acc = __fadd_rn(acc, o);
  o = __shfl_xor(acc, 4, 64); acc = __fadd_rn(acc, o);
  o = __shfl_xor(acc, 8, 64); acc = __fadd_rn(acc, o);
  if (lane == 0) dst[r] = acc;
}

// ---------------- Kernel 2: e-fragment image precompute + embT transpose (validated) ----------------
__global__ __launch_bounds__(256)
void eimg_kernel(const float* __restrict__ emb, unsigned short* __restrict__ img,
                 float* __restrict__ embT) {
  int b = blockIdx.x;
  if (b < 256) {
    int t = b * 256 + threadIdx.x;  // 65536 chunks
    int lane = t & 63;
    int tile = (t >> 6) & 1;
    int spl = (t >> 7) & 1;
    int kstep = (t >> 8) & 7;
    int cc = t >> 11;
    int code = cc * 32 + tile * 16 + (lane & 15);
    int kb = kstep * 32 + (lane >> 4) * 8;
    const float* src = emb + (size_t)code * DDIM + kb;
    union { unsigned short u[8]; uint4 v; } out;
    #pragma unroll
    for (int j = 0; j < 8; ++j) {
      float f = src[j];
      unsigned short h = f2bf_rne(f);
      if (spl == 0) out.u[j] = h;
      else {
        float r = __fadd_rn(f, -__uint_as_float((unsigned)h << 16));
        out.u[j] = f2bf_rne(r);
      }
    }
    ((uint4*)img)[t] = out.v;
  } else {
    int t = (b - 256) * 256 + threadIdx.x;  // 65536
    int base = t * 4;
    int k = base >> 10;
    int m = base & 1023;
    float4 v;
    v.x = emb[(size_t)(m + 0) * DDIM + k];
    v.y = emb[(size_t)(m + 1) * DDIM + k];
    v.z = emb[(size_t)(m + 2) * DDIM + k];
    v.w = emb[(size_t)(m + 3) * DDIM + k];
    *(float4*)&embT[base] = v;
  }
}

// ---------------- Kernel 3: MFMA split-bf16 score + argmin + FUSED gather/loss/counts ----------------
// B frags direct from global (L2-hot), depth-4 register prefetch rotation.
// Epilogue: non-flagged rows write q, counts, loss partials here (2 threads/row).
// Flagged rows (gap<=margin) -> flist; rescore_kernel emits their outputs.
__global__ __launch_bounds__(256, 2)
void score_kernel(const float* __restrict__ x, const float* __restrict__ emb,
                  const float* __restrict__ xnorm, const float* __restrict__ enorm_g,
                  const unsigned short* __restrict__ eimg,
                  int* __restrict__ idx_out, float* __restrict__ out_idxf,
                  float* __restrict__ qout, float* __restrict__ counts,
                  float* __restrict__ loss_part, float* __restrict__ np_part,
                  int* __restrict__ nflag, int* __restrict__ flist) {
  __shared__ float enorm_s[MCODES];
  __shared__ int lcount;
  __shared__ int lbase;
  __shared__ int lrows[128];
  __shared__ int sidx[128];
  __shared__ unsigned char sflag[128];
  __shared__ float red[8];

  int tid = threadIdx.x;
  int w = tid >> 6;
  int lane = tid & 63;
  int quad = lane >> 4;
  int rowBase = blockIdx.x * 128;
  int waveRow = rowBase + w * 32;

  if (tid == 0) lcount = 0;
  for (int i = tid; i < MCODES; i += 256) enorm_s[i] = enorm_g[i];
  __syncthreads();

  // ---- A-frag preload (validated layout): rows waveRow + rg*16 + (lane&15), k = ks*32 + quad*8 + j
  short8 xh[2][8], xl[2][8];
  const float* xbase = x + (size_t)(waveRow + (lane & 15)) * DDIM + quad * 8;
  #pragma unroll
  for (int rg = 0; rg < 2; ++rg) {
    #pragma unroll
    for (int ks = 0; ks < 8; ++ks) {
      const float4* p = (const float4*)(xbase + rg * 16 * DDIM + ks * 32);
      float4 v0 = p[0], v1 = p[1];
      float vv[8] = {v0.x, v0.y, v0.z, v0.w, v1.x, v1.y, v1.z, v1.w};
      short8 h8, l8;
      #pragma unroll
      for (int j = 0; j < 8; ++j) {
        unsigned short h = f2bf_rne(vv[j]);
        h8[j] = (short)h;
        float r = __fadd_rn(vv[j], -__uint_as_float((unsigned)h << 16));
        l8[j] = (short)f2bf_rne(r);
      }
      xh[rg][ks] = h8;
      xl[rg][ks] = l8;
    }
  }

  float xn[2][4];
  #pragma unroll
  for (int rg = 0; rg < 2; ++rg)
    #pragma unroll
    for (int reg = 0; reg < 4; ++reg)
      xn[rg][reg] = xnorm[waveRow + rg * 16 + quad * 4 + reg];

  float b1[2][4], b2[2][4];
  int i1[2][4];
  #pragma unroll
  for (int rg = 0; rg < 2; ++rg)
    #pragma unroll
    for (int reg = 0; reg < 4; ++reg) { b1[rg][reg] = 3.4e38f; b2[rg][reg] = 3.4e38f; i1[rg][reg] = 0; }

  // B frag pointers: chunk index = step*256 + spl*128 + t2*64 + lane, 16B each.
  const uint4* eg = ((const uint4*)eimg) + lane;

  // depth-4 prefetch rotation
  uint4 pipe[4][4];
  #pragma unroll
  for (int s = 0; s < 4; ++s) {
    const uint4* p = eg + s * 256;
    pipe[s][0] = p[0];    // eh t2=0
    pipe[s][1] = p[64];   // eh t2=1
    pipe[s][2] = p[128];  // el t2=0
    pipe[s][3] = p[192];  // el t2=1
  }

  for (int cc = 0; cc < 32; ++cc) {
    float4v acc[2][2];
    #pragma unroll
    for (int rg = 0; rg < 2; ++rg)
      #pragma unroll
      for (int t2 = 0; t2 < 2; ++t2) acc[rg][t2] = (float4v){0.f, 0.f, 0.f, 0.f};

    #pragma unroll
    for (int ks = 0; ks < 8; ++ks) {
      int step = cc * 8 + ks;
      const int pb = ks & 3;  // == step&3 (cc*8 ≡ 0 mod 4)
      uint4 c0 = pipe[pb][0], c1 = pipe[pb][1], c2 = pipe[pb][2], c3 = pipe[pb][3];
      if (step + 4 < 256) {
        const uint4* p = eg + (size_t)(step + 4) * 256;
        pipe[pb][0] = p[0];
        pipe[pb][1] = p[64];
        pipe[pb][2] = p[128];
        pipe[pb][3] = p[192];
      }
      short8 eh[2] = {as_s8(c0), as_s8(c1)};
      short8 el[2] = {as_s8(c2), as_s8(c3)};
      #pragma unroll
      for (int rg = 0; rg < 2; ++rg)
        #pragma unroll
        for (int t2 = 0; t2 < 2; ++t2) {
          acc[rg][t2] = __builtin_amdgcn_mfma_f32_16x16x32_bf16(xh[rg][ks], eh[t2], acc[rg][t2], 0, 0, 0);
          acc[rg][t2] = __builtin_amdgcn_mfma_f32_16x16x32_bf16(xl[rg][ks], eh[t2], acc[rg][t2], 0, 0, 0);
          acc[rg][t2] = __builtin_amdgcn_mfma_f32_16x16x32_bf16(xh[rg][ks], el[t2], acc[rg][t2], 0, 0, 0);
        }
    }

    // epilogue: scores + best/second-best (codes ascending: t2 then cc)
    #pragma unroll
    for (int t2 = 0; t2 < 2; ++t2) {
      int m = cc * 32 + t2 * 16 + (lane & 15);
      float en = enorm_s[m];
      #pragma unroll
      for (int rg = 0; rg < 2; ++rg)
        #pragma unroll
        for (int reg = 0; reg < 4; ++reg) {
          float T = __fadd_rn(en, xn[rg][reg]);
          float s = __fadd_rn(T, __fmul_rn(-2.0f, acc[rg][t2][reg]));
          if (s < b1[rg][reg]) { b2[rg][reg] = b1[rg][reg]; b1[rg][reg] = s; i1[rg][reg] = m; }
          else { b2[rg][reg] = fminf(b2[rg][reg], s); }
        }
    }
  }

  // cross-lane argmin over the 16 cols (lanes within a quad group)
  #pragma unroll
  for (int off = 1; off < 16; off <<= 1) {
    #pragma unroll
    for (int rg = 0; rg < 2; ++rg)
      #pragma unroll
      for (int reg = 0; reg < 4; ++reg) {
        float ob1 = __shfl_xor(b1[rg][reg], off, 64);
        float ob2 = __shfl_xor(b2[rg][reg], off, 64);
        int oi = __shfl_xor(i1[rg][reg], off, 64);
        float cb1 = b1[rg][reg], cb2 = b2[rg][reg];
        int ci = i1[rg][reg];
        float nb1, nb2; int ni;
        if (ob1 < cb1)      { nb1 = ob1; ni = oi; nb2 = fminf(cb1, ob2); }
        else if (cb1 < ob1) { nb1 = cb1; ni = ci; nb2 = fminf(ob1, cb2); }
        else                { nb1 = cb1; ni = min(ci, oi); nb2 = cb1; }  // tie -> flag
        b1[rg][reg] = nb1; b2[rg][reg] = nb2; i1[rg][reg] = ni;
      }
  }

  if ((lane & 15) == 0) {
    #pragma unroll
    for (int rg = 0; rg < 2; ++rg)
      #pragma unroll
      for (int reg = 0; reg < 4; ++reg) {
        int row = waveRow + rg * 16 + quad * 4 + reg;
        int bi = i1[rg][reg];
        idx_out[row] = bi;
        out_idxf[row] = (float)bi;
        int lr = row - rowBase;
        sidx[lr] = bi;
        int fl = (__fadd_rn(b2[rg][reg], -b1[rg][reg]) <= EPS_MARGIN) ? 1 : 0;
        sflag[lr] = (unsigned char)fl;
        if (fl) {
          int p = atomicAdd(&lcount, 1);  // LDS atomic
          lrows[p] = row;
        }
      }
  }
  __syncthreads();
  if (tid == 0 && lcount > 0) lbase = atomicAdd(nflag, lcount);
  __syncthreads();
  if (tid < lcount) flist[lbase + tid] = lrows[tid];

  // ---- fused gather + quantized_st + loss partials + counts (non-flagged rows) ----
  {
    int lr = tid >> 1;      // 0..127
    int h = tid & 1;        // half of the row
    int row = rowBase + lr;
    int id = sidx[lr];
    int fl = sflag[lr];
    const float4* xr = ((const float4*)x) + (size_t)row * 64 + h * 32;
    const float4* er = ((const float4*)emb) + (size_t)id * 64 + h * 32;
    float4* qw = ((float4*)qout) + (size_t)row * 64 + h * 32;
    float loc = 0.0f, la = 0.0f;
    #pragma unroll 8
    for (int i = 0; i < 32; ++i) {
      float4 xv = xr[i];
      float4 ev = er[i];
      float4 q;
      q.x = __fadd_rn(xv.x, __fadd_rn(ev.x, -xv.x));
      q.y = __fadd_rn(xv.y, __fadd_rn(ev.y, -xv.y));
      q.z = __fadd_rn(xv.z, __fadd_rn(ev.z, -xv.z));
      q.w = __fadd_rn(xv.w, __fadd_rn(ev.w, -xv.w));
      if (!fl) qw[i] = q;
      float d0 = xv.x - ev.x, d1 = xv.y - ev.y, d2 = xv.z - ev.z, d3 = xv.w - ev.w;
      loc += d0 * d0 + d1 * d1 + d2 * d2 + d3 * d3;
      la += fabsf(xv.x) + fabsf(xv.y) + fabsf(xv.z) + fabsf(xv.w);
    }
    // combine the two halves of the row
    loc += __shfl_xor(loc, 1, 64);
    la += __shfl_xor(la, 1, 64);
    float lsum = 0.0f, nsum = 0.0f;
    if (h == 0 && !fl) {
      float np = (la > 0.0f) ? 1.0f : 0.0f;
      lsum = (loc * (1.0f / 256.0f)) * np;
      nsum = np;
      atomicAdd(&counts[id], 1.0f);
    }
    #pragma unroll
    for (int off = 2; off < 64; off <<= 1) {  // lanes h==0 carry data; off=1 already merged
      lsum += __shfl_xor(lsum, off, 64);
      nsum += __shfl_xor(nsum, off, 64);
    }
    if (lane == 0) { red[w] = lsum; red[4 + w] = nsum; }
    __syncthreads();
    if (tid == 0) {
      loss_part[blockIdx.x] = (red[0] + red[1]) + (red[2] + red[3]);
      np_part[blockIdx.x] = (red[4] + red[5]) + (red[6] + red[7]);
    }
  }
}

// ---------------- Kernel 4: batched exact fp32 rescore + output emission for flagged rows ----------------
// Per (row,code): d = sequential fmaf k=0..255 (bit-identical validated order),
// s = fl(fl(en+xn) - 2*d), strict-<-with-lowest-index argmin. Then q/idx/counts/loss.
__global__ __launch_bounds__(256)
void rescore_kernel(const float* __restrict__ x, const float* __restrict__ emb,
                    const float* __restrict__ embT,
                    const float* __restrict__ xnorm, const float* __restrict__ enorm,
                    int* __restrict__ idx_out, float* __restrict__ out_idxf,
                    float* __restrict__ qout, float* __restrict__ counts,
                    float* __restrict__ loss_extra,
                    const int* __restrict__ nflag, const int* __restrict__ flist) {
  __shared__ float xs[RGRP][DDIM];
  __shared__ float xnr[RGRP];
  __shared__ int rown[RGRP];
  __shared__ float rv[RGRP][256];
  __shared__ int ri[RGRP][256];
  int tid = threadIdx.x;
  int n = nflag[0];

  for (int g = blockIdx.x; g * RGRP < n; g += 1024) {
    int base = g * RGRP;
    int cnt = min(RGRP, n - base);
    __syncthreads();
    if (tid < RGRP) {
      int rr = flist[base + min(tid, cnt - 1)];
      rown[tid] = rr;
      xnr[tid] = xnorm[rr];
    }
    __syncthreads();
    #pragma unroll
    for (int r = 0; r < RGRP; ++r) xs[r][tid] = x[(size_t)rown[r] * DDIM + tid];
    __syncthreads();

    float d[4][RGRP];
    #pragma unroll
    for (int c4 = 0; c4 < 4; ++c4)
      #pragma unroll
      for (int r = 0; r < RGRP; ++r) d[c4][r] = 0.0f;

    for (int k0 = 0; k0 < DDIM; k0 += 4) {
      float e[4][4];  // [kk][c4]
      #pragma unroll
      for (int kk = 0; kk < 4; ++kk)
        #pragma unroll
        for (int c4 = 0; c4 < 4; ++c4)
          e[kk][c4] = embT[(size_t)(k0 + kk) * 1024 + c4 * 256 + tid];
      float4 xv[RGRP];
      #pragma unroll
      for (int r = 0; r < RGRP; ++r) xv[r] = *(const float4*)&xs[r][k0];
      #pragma unroll
      for (int r = 0; r < RGRP; ++r) {
        float xa[4] = {xv[r].x, xv[r].y, xv[r].z, xv[r].w};
        #pragma unroll
        for (int c4 = 0; c4 < 4; ++c4) {
          d[c4][r] = fmaf(xa[0], e[0][c4], d[c4][r]);
          d[c4][r] = fmaf(xa[1], e[1][c4], d[c4][r]);
          d[c4][r] = fmaf(xa[2], e[2][c4], d[c4][r]);
          d[c4][r] = fmaf(xa[3], e[3][c4], d[c4][r]);
        }
      }
    }

    float b[RGRP]; int bi[RGRP];
    #pragma unroll
    for (int r = 0; r < RGRP; ++r) { b[r] = 3.4e38f; bi[r] = 0; }
    #pragma unroll
    for (int c4 = 0; c4 < 4; ++c4) {
      int m = c4 * 256 + tid;
      float en = enorm[m];
      #pragma unroll
      for (int r = 0; r < RGRP; ++r) {
        float T = __fadd_rn(en, xnr[r]);
        float s = __fadd_rn(T, __fmul_rn(-2.0f, d[c4][r]));
        if (s < b[r] || (s == b[r] && m < bi[r])) { b[r] = s; bi[r] = m; }
      }
    }
    #pragma unroll
    for (int r = 0; r < RGRP; ++r) { rv[r][tid] = b[r]; ri[r][tid] = bi[r]; }
    __syncthreads();
    for (int st = 128; st > 0; st >>= 1) {
      if (tid < st) {
        #pragma unroll
        for (int r = 0; r < RGRP; ++r) {
          float v = rv[r][tid + st]; int m2 = ri[r][tid + st];
          if (v < rv[r][tid] || (v == rv[r][tid] && m2 < ri[r][tid])) { rv[r][tid] = v; ri[r][tid] = m2; }
        }
      }
      __syncthreads();
    }

    // emit outputs for each flagged row in the group
    for (int r = 0; r < cnt; ++r) {
      int bfin = ri[r][0];
      int row = rown[r];
      float xv = xs[r][tid];
      float ev = emb[(size_t)bfin * DDIM + tid];
      float q = __fadd_rn(xv, __fadd_rn(ev, -xv));
      qout[(size_t)row * DDIM + tid] = q;
      float dd = xv - ev;
      rv[0][tid] = dd * dd;
      rv[1][tid] = fabsf(xv);
      __syncthreads();
      for (int st = 128; st > 0; st >>= 1) {
        if (tid < st) { rv[0][tid] += rv[0][tid + st]; rv[1][tid] += rv[1][tid + st]; }
        __syncthreads();
      }
      if (tid == 0) {
        float np = (rv[1][0] > 0.0f) ? 1.0f : 0.0f;
        atomicAdd(&loss_extra[0], (rv[0][0] * (1.0f / 256.0f)) * np);
        atomicAdd(&loss_extra[1], np);
        atomicAdd(&counts[bfin], 1.0f);
        idx_out[row] = bfin;
        out_idxf[row] = (float)bfin;
      }
      __syncthreads();
    }
  }
}

// ---------------- Kernel 5: finalize loss + perplexity ----------------
__global__ __launch_bounds__(256)
void finalize_kernel(const float* __restrict__ counts,
                     const float* __restrict__ loss_part, const float* __restrict__ np_part,
                     const float* __restrict__ loss_extra,
                     float* __restrict__ out_loss, float* __restrict__ out_perp) {
  __shared__ float red[768];
  int t = threadIdx.x;
  float esum = 0.0f, lsum = 0.0f, nsum = 0.0f;
  for (int m = t; m < MCODES; m += 256) {
    float p = counts[m] * (1.0f / 65536.0f);
    esum += p * logf(p + 1e-10f);
  }
  for (int i = t; i < NPART; i += 256) {
    lsum += loss_part[i];
    nsum += np_part[i];
  }
  red[t] = esum; red[256 + t] = lsum; red[512 + t] = nsum;
  __syncthreads();
  for (int s = 128; s > 0; s >>= 1) {
    if (t < s) {
      red[t] += red[t + s];
      red[256 + t] += red[256 + t + s];
      red[512 + t] += red[512 + t + s];
    }
    __syncthreads();
  }
  if (t == 0) {
    *out_perp = expf(-red[0]);
    float ls = red[256] + loss_extra[0];
    float ns = red[512] + loss_extra[1];
    *out_loss = 0.25f * ls / ns;
  }
}

extern "C" void kernel_launch(void* const* d_in, const int* in_sizes, int n_in,
                              void* d_out, int out_size, void* d_ws, size_t ws_size,
                              hipStream_t stream) {
  (void)in_sizes; (void)n_in; (void)out_size; (void)ws_size;
  const float* x = (const float*)d_in[0];
  const float* emb = (const float*)d_in[1];

  float* out = (float*)d_out;
  float* qst = out;                   // 16777216
  float* out_loss = out + 16777216;   // 1
  float* out_idxf = out + 16777217;   // 65536
  float* out_perp = out + 16842753;   // 1

  float* ws = (float*)d_ws;
  float* xnorm = ws;                        // 65536
  float* enorm = ws + 65536;                // 1024
  int* idx = (int*)(ws + 66560);            // 65536
  float* counts = ws + 132096;              // 1024
  float* lpart = ws + 133120;               // 512
  float* npart = ws + 133632;               // 512
  float* loss_extra = ws + 134144;          // 2
  int* nflag = (int*)(ws + 134148);         // 4
  int* flist = (int*)(ws + 134160);         // 65536
  unsigned short* eimg = (unsigned short*)(ws + 199696);  // 1 MB (524288 ushort), 16B-aligned
  float* embT = ws + 461840;                // 1 MB (262144 floats)

  norms_init_kernel<<<4160, 256, 0, stream>>>(x, emb, xnorm, enorm, counts, nflag, loss_extra);
  eimg_kernel<<<512, 256, 0, stream>>>(emb, eimg, embT);
  score_kernel<<<512, 256, 0, stream>>>(x, emb, xnorm, enorm, eimg, idx, out_idxf,
                                        qst, counts, lpart, npart, nflag, flist);
  rescore_kernel<<<1024, 256, 0, stream>>>(x, emb, embT, xnorm, enorm, idx, out_idxf,
                                           qst, counts, loss_extra, nflag, flist);
  finalize_kernel<<<1, 256, 0, stream>>>(counts, lpart, npart, loss_extra, out_loss, out_perp);
}

// Round 7
// 367.207 us; speedup vs baseline: 1.1566x; 1.1566x over previous
//
#include <hip/hip_runtime.h>

#define BROWS 65536
#define DDIM 256
#define MCODES 1024
#define EPS_MARGIN 8e-4f
#define RGRP 8
#define NPART 512

typedef __attribute__((ext_vector_type(8))) short short8;   // bf16x8 MFMA frag
typedef __attribute__((ext_vector_type(4))) float float4v;  // fp32x4 acc

__device__ inline unsigned short f2bf_rne(float f) {
  unsigned u = __float_as_uint(f);
  unsigned r = u + 0x7FFFu + ((u >> 16) & 1u);
  return (unsigned short)(r >> 16);
}

__device__ inline short8 as_s8(uint4 v) {
  union { uint4 u; short8 s; } x; x.u = v; return x.s;
}

// ---------------- Kernel 1: numpy-exact pairwise row norms + zero-init (validated) ----------------
__global__ __launch_bounds__(256)
void norms_init_kernel(const float* __restrict__ x, const float* __restrict__ emb,
                       float* __restrict__ xnorm, float* __restrict__ enorm,
                       float* __restrict__ counts, int* __restrict__ nflag,
                       float* __restrict__ loss_extra) {
  int t = blockIdx.x * 256 + threadIdx.x;
  if (t < MCODES) counts[t] = 0.0f;
  if (t == 0) *nflag = 0;
  if (t < 2) loss_extra[t] = 0.0f;
  int row = t >> 4;
  int lane = t & 15;
  const float* p;
  float* dst;
  int r;
  if (row < BROWS) { p = x + (size_t)row * DDIM; dst = xnorm; r = row; }
  else             { p = emb + (size_t)(row - BROWS) * DDIM; dst = enorm; r = row - BROWS; }
  int half = (lane >> 3) & 1;
  int j = lane & 7;
  const float* q = p + half * 128 + j;
  float v = q[0];
  float acc = __fmul_rn(v, v);
  #pragma unroll
  for (int i = 1; i < 16; ++i) {
    v = q[i * 8];
    acc = __fadd_rn(acc, __fmul_rn(v, v));
  }
  float o;
  o = __shfl_xor(acc, 1, 64); acc = __fadd_rn(acc, o);
  o = __shfl_xor(acc, 2, 64); acc = __fadd_rn(acc, o);
  o = __shfl_xor(acc, 4, 64); acc = __fadd_rn(acc, o);
  o = __shfl_xor(acc, 8, 64); acc = __fadd_rn(acc, o);
  if (lane == 0) dst[r] = acc;
}

// ---------------- Kernel 2: e-fragment image (eh only, 512KB) + embT transpose ----------------
// Image chunk t (16B): lane=t&63, t2=(t>>6)&1, step=t>>7 (ks=step&7, cc=step>>3).
// code = cc*32 + t2*16 + (lane&15); k = ks*32 + (lane>>4)*8 + j.
__global__ __launch_bounds__(256)
void eimg_kernel(const float* __restrict__ emb, unsigned short* __restrict__ img,
                 float* __restrict__ embT) {
  int b = blockIdx.x;
  if (b < 128) {
    int t = b * 256 + threadIdx.x;  // 32768 chunks
    int lane = t & 63;
    int t2 = (t >> 6) & 1;
    int step = t >> 7;
    int ks = step & 7;
    int cc = step >> 3;
    int code = cc * 32 + t2 * 16 + (lane & 15);
    int kb = ks * 32 + (lane >> 4) * 8;
    const float* src = emb + (size_t)code * DDIM + kb;
    union { unsigned short u[8]; uint4 v; } out;
    #pragma unroll
    for (int j = 0; j < 8; ++j) out.u[j] = f2bf_rne(src[j]);
    ((uint4*)img)[t] = out.v;
  } else {
    int t = (b - 128) * 256 + threadIdx.x;  // 65536
    int base = t * 4;
    int k = base >> 10;
    int m = base & 1023;
    float4 v;
    v.x = emb[(size_t)(m + 0) * DDIM + k];
    v.y = emb[(size_t)(m + 1) * DDIM + k];
    v.z = emb[(size_t)(m + 2) * DDIM + k];
    v.w = emb[(size_t)(m + 3) * DDIM + k];
    *(float4*)&embT[base] = v;
  }
}

// ---------------- Kernel 3: bf16 MFMA score + argmin + flag + FUSED coalesced gather/loss ----------------
// 1 MFMA per (rg,t2) — margin 8e-4 covers bf16-rounding error (~6e-5 rms, 10-sigma on pairs);
// flagged rows get exact fp32 rescore. LDS staging: 16KB/cc double-buffered, 1 barrier/cc.
// Fused epilogue: ONE WAVE PER ROW, lane = float4 index (the validated coalesced pattern).
__global__ __launch_bounds__(256, 2)
void score_kernel(const float* __restrict__ x, const float* __restrict__ emb,
                  const float* __restrict__ xnorm, const float* __restrict__ enorm_g,
                  const unsigned short* __restrict__ eimg,
                  int* __restrict__ idx_out, float* __restrict__ out_idxf,
                  float* __restrict__ qout, float* __restrict__ counts,
                  float* __restrict__ loss_part, float* __restrict__ np_part,
                  int* __restrict__ nflag, int* __restrict__ flist) {
  __shared__ __align__(16) unsigned short ebuf[2][8192];  // 2 x 16KB
  __shared__ float enorm_s[MCODES];
  __shared__ int lcount;
  __shared__ int lbase;
  __shared__ int lrows[128];
  __shared__ int sidx[128];
  __shared__ unsigned char sflag[128];
  __shared__ float red[8];

  int tid = threadIdx.x;
  int w = tid >> 6;
  int lane = tid & 63;
  int quad = lane >> 4;
  int rowBase = blockIdx.x * 128;
  int waveRow = rowBase + w * 32;

  if (tid == 0) lcount = 0;
  for (int i = tid; i < MCODES; i += 256) enorm_s[i] = enorm_g[i];

  // ---- A-frag preload (validated 16x16x32 layout): rows waveRow+rg*16+(lane&15), k=ks*32+quad*8+j
  short8 xh[2][8];
  const float* xbase = x + (size_t)(waveRow + (lane & 15)) * DDIM + quad * 8;
  #pragma unroll
  for (int rg = 0; rg < 2; ++rg) {
    #pragma unroll
    for (int ks = 0; ks < 8; ++ks) {
      const float4* p = (const float4*)(xbase + rg * 16 * DDIM + ks * 32);
      float4 v0 = p[0], v1 = p[1];
      float vv[8] = {v0.x, v0.y, v0.z, v0.w, v1.x, v1.y, v1.z, v1.w};
      short8 h8;
      #pragma unroll
      for (int j = 0; j < 8; ++j) h8[j] = (short)f2bf_rne(vv[j]);
      xh[rg][ks] = h8;
    }
  }

  float xn[2][4];
  #pragma unroll
  for (int rg = 0; rg < 2; ++rg)
    #pragma unroll
    for (int reg = 0; reg < 4; ++reg)
      xn[rg][reg] = xnorm[waveRow + rg * 16 + quad * 4 + reg];

  float b1[2][4], b2[2][4];
  int i1[2][4];
  #pragma unroll
  for (int rg = 0; rg < 2; ++rg)
    #pragma unroll
    for (int reg = 0; reg < 4; ++reg) { b1[rg][reg] = 3.4e38f; b2[rg][reg] = 3.4e38f; i1[rg][reg] = 0; }

  // stage one cc chunk (8192 ushorts = 16KB): wave w covers 2048 ushorts, 4 insts of 1KB.
  #define STAGE_CC(ccv, bf) do { \
    const unsigned short* g_ = eimg + (size_t)(ccv) * 8192 + w * 2048 + lane * 8; \
    unsigned short* l_ = &ebuf[(bf)][w * 2048]; \
    _Pragma("unroll") \
    for (int j_ = 0; j_ < 4; ++j_) { \
      __builtin_amdgcn_global_load_lds((const __attribute__((address_space(1))) unsigned int*)(g_ + j_ * 512), \
                                       (__attribute__((address_space(3))) unsigned int*)(l_ + j_ * 512), 16, 0, 0); \
    } \
  } while (0)

  STAGE_CC(0, 0);

  for (int cc = 0; cc < 32; ++cc) {
    int buf = cc & 1;
    __syncthreads();                 // stage(cc) visible; prev buf free
    if (cc < 31) STAGE_CC(cc + 1, buf ^ 1);

    float4v acc[2][2];
    #pragma unroll
    for (int rg = 0; rg < 2; ++rg)
      #pragma unroll
      for (int t2 = 0; t2 < 2; ++t2) acc[rg][t2] = (float4v){0.f, 0.f, 0.f, 0.f};

    #pragma unroll
    for (int ks = 0; ks < 8; ++ks) {
      short8 eh[2];
      #pragma unroll
      for (int t2 = 0; t2 < 2; ++t2)
        eh[t2] = *(const short8*)&ebuf[buf][(ks * 2 + t2) * 512 + lane * 8];
      #pragma unroll
      for (int rg = 0; rg < 2; ++rg)
        #pragma unroll
        for (int t2 = 0; t2 < 2; ++t2)
          acc[rg][t2] = __builtin_amdgcn_mfma_f32_16x16x32_bf16(xh[rg][ks], eh[t2], acc[rg][t2], 0, 0, 0);
    }

    // epilogue: s = fl(T - 2*acc) via single fma (product exact -> identical rounding)
    #pragma unroll
    for (int t2 = 0; t2 < 2; ++t2) {
      int m = cc * 32 + t2 * 16 + (lane & 15);
      float en = enorm_s[m];
      #pragma unroll
      for (int rg = 0; rg < 2; ++rg)
        #pragma unroll
        for (int reg = 0; reg < 4; ++reg) {
          float T = __fadd_rn(en, xn[rg][reg]);
          float s = fmaf(-2.0f, acc[rg][t2][reg], T);
          if (s < b1[rg][reg]) { b2[rg][reg] = b1[rg][reg]; b1[rg][reg] = s; i1[rg][reg] = m; }
          else { b2[rg][reg] = fminf(b2[rg][reg], s); }
        }
    }
  }

  // cross-lane argmin over the 16 cols
  #pragma unroll
  for (int off = 1; off < 16; off <<= 1) {
    #pragma unroll
    for (int rg = 0; rg < 2; ++rg)
      #pragma unroll
      for (int reg = 0; reg < 4; ++reg) {
        float ob1 = __shfl_xor(b1[rg][reg], off, 64);
        float ob2 = __shfl_xor(b2[rg][reg], off, 64);
        int oi = __shfl_xor(i1[rg][reg], off, 64);
        float cb1 = b1[rg][reg], cb2 = b2[rg][reg];
        int ci = i1[rg][reg];
        float nb1, nb2; int ni;
        if (ob1 < cb1)      { nb1 = ob1; ni = oi; nb2 = fminf(cb1, ob2); }
        else if (cb1 < ob1) { nb1 = cb1; ni = ci; nb2 = fminf(ob1, cb2); }
        else                { nb1 = cb1; ni = min(ci, oi); nb2 = cb1; }  // tie -> flag
        b1[rg][reg] = nb1; b2[rg][reg] = nb2; i1[rg][reg] = ni;
      }
  }

  if ((lane & 15) == 0) {
    #pragma unroll
    for (int rg = 0; rg < 2; ++rg)
      #pragma unroll
      for (int reg = 0; reg < 4; ++reg) {
        int row = waveRow + rg * 16 + quad * 4 + reg;
        int bi = i1[rg][reg];
        idx_out[row] = bi;
        out_idxf[row] = (float)bi;
        int lr = row - rowBase;
        sidx[lr] = bi;
        int fl = (__fadd_rn(b2[rg][reg], -b1[rg][reg]) <= EPS_MARGIN) ? 1 : 0;
        sflag[lr] = (unsigned char)fl;
        if (fl) {
          int p = atomicAdd(&lcount, 1);
          lrows[p] = row;
        }
      }
  }
  __syncthreads();
  if (tid == 0 && lcount > 0) lbase = atomicAdd(nflag, lcount);
  __syncthreads();
  if (tid < lcount) flist[lbase + tid] = lrows[tid];

  // ---- fused gather: ONE WAVE PER ROW, lane = float4 index (coalesced 1KB per access) ----
  float lsum = 0.0f, nsum = 0.0f;
  for (int it = 0; it < 32; ++it) {
    int lr = w * 32 + it;
    int row = rowBase + lr;
    int id = sidx[lr];
    int fl = sflag[lr];
    float4 xv = ((const float4*)x)[(size_t)row * 64 + lane];
    float4 ev = ((const float4*)emb)[(size_t)id * 64 + lane];
    float4 q;
    q.x = __fadd_rn(xv.x, __fadd_rn(ev.x, -xv.x));
    q.y = __fadd_rn(xv.y, __fadd_rn(ev.y, -xv.y));
    q.z = __fadd_rn(xv.z, __fadd_rn(ev.z, -xv.z));
    q.w = __fadd_rn(xv.w, __fadd_rn(ev.w, -xv.w));
    ((float4*)qout)[(size_t)row * 64 + lane] = q;

    float d0 = xv.x - ev.x, d1 = xv.y - ev.y, d2 = xv.z - ev.z, d3 = xv.w - ev.w;
    float loc = d0 * d0 + d1 * d1 + d2 * d2 + d3 * d3;
    float la = fabsf(xv.x) + fabsf(xv.y) + fabsf(xv.z) + fabsf(xv.w);
    #pragma unroll
    for (int off = 32; off > 0; off >>= 1) {
      loc += __shfl_xor(loc, off, 64);
      la += __shfl_xor(la, off, 64);
    }
    if (lane == 0 && !fl) {
      float np = (la > 0.0f) ? 1.0f : 0.0f;
      lsum += (loc * (1.0f / 256.0f)) * np;
      nsum += np;
      atomicAdd(&counts[id], 1.0f);
    }
  }
  if (lane == 0) { red[w] = lsum; red[4 + w] = nsum; }
  __syncthreads();
  if (tid == 0) {
    loss_part[blockIdx.x] = (red[0] + red[1]) + (red[2] + red[3]);
    np_part[blockIdx.x] = (red[4] + red[5]) + (red[6] + red[7]);
  }
  #undef STAGE_CC
}

// ---------------- Kernel 4: batched exact fp32 rescore + outputs for flagged rows (validated r6) ----------------
__global__ __launch_bounds__(256)
void rescore_kernel(const float* __restrict__ x, const float* __restrict__ emb,
                    const float* __restrict__ embT,
                    const float* __restrict__ xnorm, const float* __restrict__ enorm,
                    int* __restrict__ idx_out, float* __restrict__ out_idxf,
                    float* __restrict__ qout, float* __restrict__ counts,
                    float* __restrict__ loss_extra,
                    const int* __restrict__ nflag, const int* __restrict__ flist) {
  __shared__ float xs[RGRP][DDIM];
  __shared__ float xnr[RGRP];
  __shared__ int rown[RGRP];
  __shared__ float rv[RGRP][256];
  __shared__ int ri[RGRP][256];
  int tid = threadIdx.x;
  int n = nflag[0];

  for (int g = blockIdx.x; g * RGRP < n; g += 1024) {
    int base = g * RGRP;
    int cnt = min(RGRP, n - base);
    __syncthreads();
    if (tid < RGRP) {
      int rr = flist[base + min(tid, cnt - 1)];
      rown[tid] = rr;
      xnr[tid] = xnorm[rr];
    }
    __syncthreads();
    #pragma unroll
    for (int r = 0; r < RGRP; ++r) xs[r][tid] = x[(size_t)rown[r] * DDIM + tid];
    __syncthreads();

    float d[4][RGRP];
    #pragma unroll
    for (int c4 = 0; c4 < 4; ++c4)
      #pragma unroll
      for (int r = 0; r < RGRP; ++r) d[c4][r] = 0.0f;

    for (int k0 = 0; k0 < DDIM; k0 += 4) {
      float e[4][4];  // [kk][c4]
      #pragma unroll
      for (int kk = 0; kk < 4; ++kk)
        #pragma unroll
        for (int c4 = 0; c4 < 4; ++c4)
          e[kk][c4] = embT[(size_t)(k0 + kk) * 1024 + c4 * 256 + tid];
      float4 xv[RGRP];
      #pragma unroll
      for (int r = 0; r < RGRP; ++r) xv[r] = *(const float4*)&xs[r][k0];
      #pragma unroll
      for (int r = 0; r < RGRP; ++r) {
        float xa[4] = {xv[r].x, xv[r].y, xv[r].z, xv[r].w};
        #pragma unroll
        for (int c4 = 0; c4 < 4; ++c4) {
          d[c4][r] = fmaf(xa[0], e[0][c4], d[c4][r]);
          d[c4][r] = fmaf(xa[1], e[1][c4], d[c4][r]);
          d[c4][r] = fmaf(xa[2], e[2][c4], d[c4][r]);
          d[c4][r] = fmaf(xa[3], e[3][c4], d[c4][r]);
        }
      }
    }

    float b[RGRP]; int bi[RGRP];
    #pragma unroll
    for (int r = 0; r < RGRP; ++r) { b[r] = 3.4e38f; bi[r] = 0; }
    #pragma unroll
    for (int c4 = 0; c4 < 4; ++c4) {
      int m = c4 * 256 + tid;
      float en = enorm[m];
      #pragma unroll
      for (int r = 0; r < RGRP; ++r) {
        float T = __fadd_rn(en, xnr[r]);
        float s = __fadd_rn(T, __fmul_rn(-2.0f, d[c4][r]));
        if (s < b[r] || (s == b[r] && m < bi[r])) { b[r] = s; bi[r] = m; }
      }
    }
    #pragma unroll
    for (int r = 0; r < RGRP; ++r) { rv[r][tid] = b[r]; ri[r][tid] = bi[r]; }
    __syncthreads();
    for (int st = 128; st > 0; st >>= 1) {
      if (tid < st) {
        #pragma unroll
        for (int r = 0; r < RGRP; ++r) {
          float v = rv[r][tid + st]; int m2 = ri[r][tid + st];
          if (v < rv[r][tid] || (v == rv[r][tid] && m2 < ri[r][tid])) { rv[r][tid] = v; ri[r][tid] = m2; }
        }
      }
      __syncthreads();
    }

    for (int r = 0; r < cnt; ++r) {
      int bfin = ri[r][0];
      int row = rown[r];
      float xv = xs[r][tid];
      float ev = emb[(size_t)bfin * DDIM + tid];
      float q = __fadd_rn(xv, __fadd_rn(ev, -xv));
      qout[(size_t)row * DDIM + tid] = q;
      float dd = xv - ev;
      rv[0][tid] = dd * dd;
      rv[1][tid] = fabsf(xv);
      __syncthreads();
      for (int st = 128; st > 0; st >>= 1) {
        if (tid < st) { rv[0][tid] += rv[0][tid + st]; rv[1][tid] += rv[1][tid + st]; }
        __syncthreads();
      }
      if (tid == 0) {
        float np = (rv[1][0] > 0.0f) ? 1.0f : 0.0f;
        atomicAdd(&loss_extra[0], (rv[0][0] * (1.0f / 256.0f)) * np);
        atomicAdd(&loss_extra[1], np);
        atomicAdd(&counts[bfin], 1.0f);
        idx_out[row] = bfin;
        out_idxf[row] = (float)bfin;
      }
      __syncthreads();
    }
  }
}

// ---------------- Kernel 5: finalize loss + perplexity ----------------
__global__ __launch_bounds__(256)
void finalize_kernel(const float* __restrict__ counts,
                     const float* __restrict__ loss_part, const float* __restrict__ np_part,
                     const float* __restrict__ loss_extra,
                     float* __restrict__ out_loss, float* __restrict__ out_perp) {
  __shared__ float red[768];
  int t = threadIdx.x;
  float esum = 0.0f, lsum = 0.0f, nsum = 0.0f;
  for (int m = t; m < MCODES; m += 256) {
    float p = counts[m] * (1.0f / 65536.0f);
    esum += p * logf(p + 1e-10f);
  }
  for (int i = t; i < NPART; i += 256) {
    lsum += loss_part[i];
    nsum += np_part[i];
  }
  red[t] = esum; red[256 + t] = lsum; red[512 + t] = nsum;
  __syncthreads();
  for (int s = 128; s > 0; s >>= 1) {
    if (t < s) {
      red[t] += red[t + s];
      red[256 + t] += red[256 + t + s];
      red[512 + t] += red[512 + t + s];
    }
    __syncthreads();
  }
  if (t == 0) {
    *out_perp = expf(-red[0]);
    float ls = red[256] + loss_extra[0];
    float ns = red[512] + loss_extra[1];
    *out_loss = 0.25f * ls / ns;
  }
}

extern "C" void kernel_launch(void* const* d_in, const int* in_sizes, int n_in,
                              void* d_out, int out_size, void* d_ws, size_t ws_size,
                              hipStream_t stream) {
  (void)in_sizes; (void)n_in; (void)out_size; (void)ws_size;
  const float* x = (const float*)d_in[0];
  const float* emb = (const float*)d_in[1];

  float* out = (float*)d_out;
  float* qst = out;                   // 16777216
  float* out_loss = out + 16777216;   // 1
  float* out_idxf = out + 16777217;   // 65536
  float* out_perp = out + 16842753;   // 1

  float* ws = (float*)d_ws;
  float* xnorm = ws;                        // 65536
  float* enorm = ws + 65536;                // 1024
  int* idx = (int*)(ws + 66560);            // 65536
  float* counts = ws + 132096;              // 1024
  float* lpart = ws + 133120;               // 512
  float* npart = ws + 133632;               // 512
  float* loss_extra = ws + 134144;          // 2
  int* nflag = (int*)(ws + 134148);         // 1
  int* flist = (int*)(ws + 134160);         // 65536
  unsigned short* eimg = (unsigned short*)(ws + 199696);  // 512 KB (262144 ushort), 16B-aligned
  float* embT = ws + 330768;                // 1 MB (262144 floats)

  norms_init_kernel<<<4160, 256, 0, stream>>>(x, emb, xnorm, enorm, counts, nflag, loss_extra);
  eimg_kernel<<<384, 256, 0, stream>>>(emb, eimg, embT);
  score_kernel<<<512, 256, 0, stream>>>(x, emb, xnorm, enorm, eimg, idx, out_idxf,
                                        qst, counts, lpart, npart, nflag, flist);
  rescore_kernel<<<1024, 256, 0, stream>>>(x, emb, embT, xnorm, enorm, idx, out_idxf,
                                           qst, counts, loss_extra, nflag, flist);
  finalize_kernel<<<1, 256, 0, stream>>>(counts, lpart, npart, loss_extra, out_loss, out_perp);
}

// Round 8
// 291.962 us; speedup vs baseline: 1.4547x; 1.2577x over previous
//
#include <hip/hip_runtime.h>

#define BROWS 65536
#define DDIM 256
#define MCODES 1024
#define EPS_MARGIN 1e-5f
#define RGRP 8
#define NPART 512

typedef __attribute__((ext_vector_type(8))) short short8;   // bf16x8 MFMA frag
typedef __attribute__((ext_vector_type(4))) float float4v;  // fp32x4 acc

__device__ inline unsigned short f2bf_rne(float f) {
  unsigned u = __float_as_uint(f);
  unsigned r = u + 0x7FFFu + ((u >> 16) & 1u);
  return (unsigned short)(r >> 16);
}

// ---------------- Kernel 1: numpy-exact pairwise row norms + zero-init (validated) ----------------
__global__ __launch_bounds__(256)
void norms_init_kernel(const float* __restrict__ x, const float* __restrict__ emb,
                       float* __restrict__ xnorm, float* __restrict__ enorm,
                       float* __restrict__ counts, int* __restrict__ nflag,
                       float* __restrict__ loss_extra) {
  int t = blockIdx.x * 256 + threadIdx.x;
  if (t < MCODES) counts[t] = 0.0f;
  if (t == 0) *nflag = 0;
  if (t < 2) loss_extra[t] = 0.0f;
  int row = t >> 4;
  int lane = t & 15;
  const float* p;
  float* dst;
  int r;
  if (row < BROWS) { p = x + (size_t)row * DDIM; dst = xnorm; r = row; }
  else             { p = emb + (size_t)(row - BROWS) * DDIM; dst = enorm; r = row - BROWS; }
  int half = (lane >> 3) & 1;
  int j = lane & 7;
  const float* q = p + half * 128 + j;
  float v = q[0];
  float acc = __fmul_rn(v, v);
  #pragma unroll
  for (int i = 1; i < 16; ++i) {
    v = q[i * 8];
    acc = __fadd_rn(acc, __fmul_rn(v, v));
  }
  float o;
  o = __shfl_xor(acc, 1, 64); acc = __fadd_rn(acc, o);
  o = __shfl_xor(acc, 2, 64); acc = __fadd_rn(acc, o);
  o = __shfl_xor(acc, 4, 64); acc = __fadd_rn(acc, o);
  o = __shfl_xor(acc, 8, 64); acc = __fadd_rn(acc, o);
  if (lane == 0) dst[r] = acc;
}

// ---------------- Kernel 2: full hi/lo e-fragment image (1MB) + embT transpose (validated r4) ----------------
// Image: chunk t (16B): lane=t&63, tile=(t>>6)&1, spl=(t>>7)&1, kstep=(t>>8)&7, cc=t>>11.
// code = cc*32 + tile*16 + (lane&15); k = kstep*32 + (lane>>4)*8 + j.
__global__ __launch_bounds__(256)
void eimg_kernel(const float* __restrict__ emb, unsigned short* __restrict__ img,
                 float* __restrict__ embT) {
  int b = blockIdx.x;
  if (b < 256) {
    int t = b * 256 + threadIdx.x;  // 65536 chunks
    int lane = t & 63;
    int tile = (t >> 6) & 1;
    int spl = (t >> 7) & 1;
    int kstep = (t >> 8) & 7;
    int cc = t >> 11;
    int code = cc * 32 + tile * 16 + (lane & 15);
    int kb = kstep * 32 + (lane >> 4) * 8;
    const float* src = emb + (size_t)code * DDIM + kb;
    union { unsigned short u[8]; uint4 v; } out;
    #pragma unroll
    for (int j = 0; j < 8; ++j) {
      float f = src[j];
      unsigned short h = f2bf_rne(f);
      if (spl == 0) out.u[j] = h;
      else {
        float r = __fadd_rn(f, -__uint_as_float((unsigned)h << 16));
        out.u[j] = f2bf_rne(r);
      }
    }
    ((uint4*)img)[t] = out.v;
  } else {
    int t = (b - 256) * 256 + threadIdx.x;  // 65536
    int base = t * 4;
    int k = base >> 10;
    int m = base & 1023;
    float4 v;
    v.x = emb[(size_t)(m + 0) * DDIM + k];
    v.y = emb[(size_t)(m + 1) * DDIM + k];
    v.z = emb[(size_t)(m + 2) * DDIM + k];
    v.w = emb[(size_t)(m + 3) * DDIM + k];
    *(float4*)&embT[base] = v;
  }
}

// ---------------- Kernel 3: 3-MFMA split-bf16 score (r4 core) + flag + FUSED coalesced gather (r7 tail) ----------------
// Dot = xh*eh + xl*eh + xh*el (error ~2e-7 << half-ulp of score grid 3.05e-5).
// Margin 1e-5 -> flags are exact fp32 ties only (~1% rows); rescore resolves them.
// LDS staging: 32KB/cc, double-buffered, ONE barrier per cc.
__global__ __launch_bounds__(256, 2)
void score_kernel(const float* __restrict__ x, const float* __restrict__ emb,
                  const float* __restrict__ xnorm, const float* __restrict__ enorm_g,
                  const unsigned short* __restrict__ eimg,
                  int* __restrict__ idx_out, float* __restrict__ out_idxf,
                  float* __restrict__ qout, float* __restrict__ counts,
                  float* __restrict__ loss_part, float* __restrict__ np_part,
                  int* __restrict__ nflag, int* __restrict__ flist) {
  __shared__ __align__(16) unsigned short ebuf[2][16384];  // 2 x 32KB
  __shared__ float enorm_s[MCODES];
  __shared__ int lcount;
  __shared__ int lbase;
  __shared__ int lrows[128];
  __shared__ int sidx[128];
  __shared__ unsigned char sflag[128];
  __shared__ float red[8];

  int tid = threadIdx.x;
  int w = tid >> 6;
  int lane = tid & 63;
  int quad = lane >> 4;
  int rowBase = blockIdx.x * 128;
  int waveRow = rowBase + w * 32;

  if (tid == 0) lcount = 0;
  for (int i = tid; i < MCODES; i += 256) enorm_s[i] = enorm_g[i];

  // ---- A-frag preload (validated layout): rows waveRow + rg*16 + (lane&15), k = ks*32 + quad*8 + j
  short8 xh[2][8], xl[2][8];
  const float* xbase = x + (size_t)(waveRow + (lane & 15)) * DDIM + quad * 8;
  #pragma unroll
  for (int rg = 0; rg < 2; ++rg) {
    #pragma unroll
    for (int ks = 0; ks < 8; ++ks) {
      const float4* p = (const float4*)(xbase + rg * 16 * DDIM + ks * 32);
      float4 v0 = p[0], v1 = p[1];
      float vv[8] = {v0.x, v0.y, v0.z, v0.w, v1.x, v1.y, v1.z, v1.w};
      short8 h8, l8;
      #pragma unroll
      for (int j = 0; j < 8; ++j) {
        unsigned short h = f2bf_rne(vv[j]);
        h8[j] = (short)h;
        float r = __fadd_rn(vv[j], -__uint_as_float((unsigned)h << 16));
        l8[j] = (short)f2bf_rne(r);
      }
      xh[rg][ks] = h8;
      xl[rg][ks] = l8;
    }
  }

  float xn[2][4];
  #pragma unroll
  for (int rg = 0; rg < 2; ++rg)
    #pragma unroll
    for (int reg = 0; reg < 4; ++reg)
      xn[rg][reg] = xnorm[waveRow + rg * 16 + quad * 4 + reg];

  float b1[2][4], b2[2][4];
  int i1[2][4];
  #pragma unroll
  for (int rg = 0; rg < 2; ++rg)
    #pragma unroll
    for (int reg = 0; reg < 4; ++reg) { b1[rg][reg] = 3.4e38f; b2[rg][reg] = 3.4e38f; i1[rg][reg] = 0; }

  // stage one full cc chunk (16384 shorts = 32KB): wave w covers 4096 shorts, 8 insts of 1KB.
  #define STAGE_CC(ccv, bf) do { \
    const unsigned short* g_ = eimg + (size_t)(ccv) * 16384 + w * 4096 + lane * 8; \
    unsigned short* l_ = &ebuf[(bf)][w * 4096]; \
    _Pragma("unroll") \
    for (int j_ = 0; j_ < 8; ++j_) { \
      __builtin_amdgcn_global_load_lds((const __attribute__((address_space(1))) unsigned int*)(g_ + j_ * 512), \
                                       (__attribute__((address_space(3))) unsigned int*)(l_ + j_ * 512), 16, 0, 0); \
    } \
  } while (0)

  STAGE_CC(0, 0);

  for (int cc = 0; cc < 32; ++cc) {
    int buf = cc & 1;
    __syncthreads();                 // stage(cc) visible; prev buf free
    if (cc < 31) STAGE_CC(cc + 1, buf ^ 1);

    float4v acc[2][2];
    #pragma unroll
    for (int rg = 0; rg < 2; ++rg)
      #pragma unroll
      for (int t2 = 0; t2 < 2; ++t2) acc[rg][t2] = (float4v){0.f, 0.f, 0.f, 0.f};

    #pragma unroll
    for (int ks = 0; ks < 8; ++ks) {
      const unsigned short* sb = &ebuf[buf][ks * 2048];
      short8 eh[2], el[2];
      #pragma unroll
      for (int t2 = 0; t2 < 2; ++t2) {
        eh[t2] = *(const short8*)&sb[0 * 1024 + t2 * 512 + lane * 8];
        el[t2] = *(const short8*)&sb[1 * 1024 + t2 * 512 + lane * 8];
      }
      #pragma unroll
      for (int rg = 0; rg < 2; ++rg)
        #pragma unroll
        for (int t2 = 0; t2 < 2; ++t2) {
          acc[rg][t2] = __builtin_amdgcn_mfma_f32_16x16x32_bf16(xh[rg][ks], eh[t2], acc[rg][t2], 0, 0, 0);
          acc[rg][t2] = __builtin_amdgcn_mfma_f32_16x16x32_bf16(xl[rg][ks], eh[t2], acc[rg][t2], 0, 0, 0);
          acc[rg][t2] = __builtin_amdgcn_mfma_f32_16x16x32_bf16(xh[rg][ks], el[t2], acc[rg][t2], 0, 0, 0);
        }
    }

    // epilogue: s = fl(fl(en+xn) - 2*acc); -2*acc exact, single rounded subtract
    #pragma unroll
    for (int t2 = 0; t2 < 2; ++t2) {
      int m = cc * 32 + t2 * 16 + (lane & 15);
      float en = enorm_s[m];
      #pragma unroll
      for (int rg = 0; rg < 2; ++rg)
        #pragma unroll
        for (int reg = 0; reg < 4; ++reg) {
          float T = __fadd_rn(en, xn[rg][reg]);
          float s = __fadd_rn(T, __fmul_rn(-2.0f, acc[rg][t2][reg]));
          if (s < b1[rg][reg]) { b2[rg][reg] = b1[rg][reg]; b1[rg][reg] = s; i1[rg][reg] = m; }
          else { b2[rg][reg] = fminf(b2[rg][reg], s); }
        }
    }
  }

  // cross-lane argmin over the 16 cols
  #pragma unroll
  for (int off = 1; off < 16; off <<= 1) {
    #pragma unroll
    for (int rg = 0; rg < 2; ++rg)
      #pragma unroll
      for (int reg = 0; reg < 4; ++reg) {
        float ob1 = __shfl_xor(b1[rg][reg], off, 64);
        float ob2 = __shfl_xor(b2[rg][reg], off, 64);
        int oi = __shfl_xor(i1[rg][reg], off, 64);
        float cb1 = b1[rg][reg], cb2 = b2[rg][reg];
        int ci = i1[rg][reg];
        float nb1, nb2; int ni;
        if (ob1 < cb1)      { nb1 = ob1; ni = oi; nb2 = fminf(cb1, ob2); }
        else if (cb1 < ob1) { nb1 = cb1; ni = ci; nb2 = fminf(ob1, cb2); }
        else                { nb1 = cb1; ni = min(ci, oi); nb2 = cb1; }  // tie -> flag
        b1[rg][reg] = nb1; b2[rg][reg] = nb2; i1[rg][reg] = ni;
      }
  }

  if ((lane & 15) == 0) {
    #pragma unroll
    for (int rg = 0; rg < 2; ++rg)
      #pragma unroll
      for (int reg = 0; reg < 4; ++reg) {
        int row = waveRow + rg * 16 + quad * 4 + reg;
        int bi = i1[rg][reg];
        idx_out[row] = bi;
        out_idxf[row] = (float)bi;
        int lr = row - rowBase;
        sidx[lr] = bi;
        int fl = (__fadd_rn(b2[rg][reg], -b1[rg][reg]) <= EPS_MARGIN) ? 1 : 0;
        sflag[lr] = (unsigned char)fl;
        if (fl) {
          int p = atomicAdd(&lcount, 1);
          lrows[p] = row;
        }
      }
  }
  __syncthreads();
  if (tid == 0 && lcount > 0) lbase = atomicAdd(nflag, lcount);
  __syncthreads();
  if (tid < lcount) flist[lbase + tid] = lrows[tid];

  // ---- fused gather (validated r7): ONE WAVE PER ROW, lane = float4 index ----
  float lsum = 0.0f, nsum = 0.0f;
  for (int it = 0; it < 32; ++it) {
    int lr = w * 32 + it;
    int row = rowBase + lr;
    int id = sidx[lr];
    int fl = sflag[lr];
    float4 xv = ((const float4*)x)[(size_t)row * 64 + lane];
    float4 ev = ((const float4*)emb)[(size_t)id * 64 + lane];
    float4 q;
    q.x = __fadd_rn(xv.x, __fadd_rn(ev.x, -xv.x));
    q.y = __fadd_rn(xv.y, __fadd_rn(ev.y, -xv.y));
    q.z = __fadd_rn(xv.z, __fadd_rn(ev.z, -xv.z));
    q.w = __fadd_rn(xv.w, __fadd_rn(ev.w, -xv.w));
    ((float4*)qout)[(size_t)row * 64 + lane] = q;

    float d0 = xv.x - ev.x, d1 = xv.y - ev.y, d2 = xv.z - ev.z, d3 = xv.w - ev.w;
    float loc = d0 * d0 + d1 * d1 + d2 * d2 + d3 * d3;
    float la = fabsf(xv.x) + fabsf(xv.y) + fabsf(xv.z) + fabsf(xv.w);
    #pragma unroll
    for (int off = 32; off > 0; off >>= 1) {
      loc += __shfl_xor(loc, off, 64);
      la += __shfl_xor(la, off, 64);
    }
    if (lane == 0 && !fl) {
      float np = (la > 0.0f) ? 1.0f : 0.0f;
      lsum += (loc * (1.0f / 256.0f)) * np;
      nsum += np;
      atomicAdd(&counts[id], 1.0f);
    }
  }
  if (lane == 0) { red[w] = lsum; red[4 + w] = nsum; }
  __syncthreads();
  if (tid == 0) {
    loss_part[blockIdx.x] = (red[0] + red[1]) + (red[2] + red[3]);
    np_part[blockIdx.x] = (red[4] + red[5]) + (red[6] + red[7]);
  }
  #undef STAGE_CC
}

// ---------------- Kernel 4: batched exact fp32 rescore + outputs for flagged rows (validated r6/r7) ----------------
__global__ __launch_bounds__(256)
void rescore_kernel(const float* __restrict__ x, const float* __restrict__ emb,
                    const float* __restrict__ embT,
                    const float* __restrict__ xnorm, const float* __restrict__ enorm,
                    int* __restrict__ idx_out, float* __restrict__ out_idxf,
                    float* __restrict__ qout, float* __restrict__ counts,
                    float* __restrict__ loss_extra,
                    const int* __restrict__ nflag, const int* __restrict__ flist) {
  __shared__ float xs[RGRP][DDIM];
  __shared__ float xnr[RGRP];
  __shared__ int rown[RGRP];
  __shared__ float rv[RGRP][256];
  __shared__ int ri[RGRP][256];
  int tid = threadIdx.x;
  int n = nflag[0];

  for (int g = blockIdx.x; g * RGRP < n; g += 1024) {
    int base = g * RGRP;
    int cnt = min(RGRP, n - base);
    __syncthreads();
    if (tid < RGRP) {
      int rr = flist[base + min(tid, cnt - 1)];
      rown[tid] = rr;
      xnr[tid] = xnorm[rr];
    }
    __syncthreads();
    #pragma unroll
    for (int r = 0; r < RGRP; ++r) xs[r][tid] = x[(size_t)rown[r] * DDIM + tid];
    __syncthreads();

    float d[4][RGRP];
    #pragma unroll
    for (int c4 = 0; c4 < 4; ++c4)
      #pragma unroll
      for (int r = 0; r < RGRP; ++r) d[c4][r] = 0.0f;

    for (int k0 = 0; k0 < DDIM; k0 += 4) {
      float e[4][4];  // [kk][c4]
      #pragma unroll
      for (int kk = 0; kk < 4; ++kk)
        #pragma unroll
        for (int c4 = 0; c4 < 4; ++c4)
          e[kk][c4] = embT[(size_t)(k0 + kk) * 1024 + c4 * 256 + tid];
      float4 xv[RGRP];
      #pragma unroll
      for (int r = 0; r < RGRP; ++r) xv[r] = *(const float4*)&xs[r][k0];
      #pragma unroll
      for (int r = 0; r < RGRP; ++r) {
        float xa[4] = {xv[r].x, xv[r].y, xv[r].z, xv[r].w};
        #pragma unroll
        for (int c4 = 0; c4 < 4; ++c4) {
          d[c4][r] = fmaf(xa[0], e[0][c4], d[c4][r]);
          d[c4][r] = fmaf(xa[1], e[1][c4], d[c4][r]);
          d[c4][r] = fmaf(xa[2], e[2][c4], d[c4][r]);
          d[c4][r] = fmaf(xa[3], e[3][c4], d[c4][r]);
        }
      }
    }

    float b[RGRP]; int bi[RGRP];
    #pragma unroll
    for (int r = 0; r < RGRP; ++r) { b[r] = 3.4e38f; bi[r] = 0; }
    #pragma unroll
    for (int c4 = 0; c4 < 4; ++c4) {
      int m = c4 * 256 + tid;
      float en = enorm[m];
      #pragma unroll
      for (int r = 0; r < RGRP; ++r) {
        float T = __fadd_rn(en, xnr[r]);
        float s = __fadd_rn(T, __fmul_rn(-2.0f, d[c4][r]));
        if (s < b[r] || (s == b[r] && m < bi[r])) { b[r] = s; bi[r] = m; }
      }
    }
    #pragma unroll
    for (int r = 0; r < RGRP; ++r) { rv[r][tid] = b[r]; ri[r][tid] = bi[r]; }
    __syncthreads();
    for (int st = 128; st > 0; st >>= 1) {
      if (tid < st) {
        #pragma unroll
        for (int r = 0; r < RGRP; ++r) {
          float v = rv[r][tid + st]; int m2 = ri[r][tid + st];
          if (v < rv[r][tid] || (v == rv[r][tid] && m2 < ri[r][tid])) { rv[r][tid] = v; ri[r][tid] = m2; }
        }
      }
      __syncthreads();
    }

    for (int r = 0; r < cnt; ++r) {
      int bfin = ri[r][0];
      int row = rown[r];
      float xv = xs[r][tid];
      float ev = emb[(size_t)bfin * DDIM + tid];
      float q = __fadd_rn(xv, __fadd_rn(ev, -xv));
      qout[(size_t)row * DDIM + tid] = q;
      float dd = xv - ev;
      rv[0][tid] = dd * dd;
      rv[1][tid] = fabsf(xv);
      __syncthreads();
      for (int st = 128; st > 0; st >>= 1) {
        if (tid < st) { rv[0][tid] += rv[0][tid + st]; rv[1][tid] += rv[1][tid + st]; }
        __syncthreads();
      }
      if (tid == 0) {
        float np = (rv[1][0] > 0.0f) ? 1.0f : 0.0f;
        atomicAdd(&loss_extra[0], (rv[0][0] * (1.0f / 256.0f)) * np);
        atomicAdd(&loss_extra[1], np);
        atomicAdd(&counts[bfin], 1.0f);
        idx_out[row] = bfin;
        out_idxf[row] = (float)bfin;
      }
      __syncthreads();
    }
  }
}

// ---------------- Kernel 5: finalize loss + perplexity ----------------
__global__ __launch_bounds__(256)
void finalize_kernel(const float* __restrict__ counts,
                     const float* __restrict__ loss_part, const float* __restrict__ np_part,
                     const float* __restrict__ loss_extra,
                     float* __restrict__ out_loss, float* __restrict__ out_perp) {
  __shared__ float red[768];
  int t = threadIdx.x;
  float esum = 0.0f, lsum = 0.0f, nsum = 0.0f;
  for (int m = t; m < MCODES; m += 256) {
    float p = counts[m] * (1.0f / 65536.0f);
    esum += p * logf(p + 1e-10f);
  }
  for (int i = t; i < NPART; i += 256) {
    lsum += loss_part[i];
    nsum += np_part[i];
  }
  red[t] = esum; red[256 + t] = lsum; red[512 + t] = nsum;
  __syncthreads();
  for (int s = 128; s > 0; s >>= 1) {
    if (t < s) {
      red[t] += red[t + s];
      red[256 + t] += red[256 + t + s];
      red[512 + t] += red[512 + t + s];
    }
    __syncthreads();
  }
  if (t == 0) {
    *out_perp = expf(-red[0]);
    float ls = red[256] + loss_extra[0];
    float ns = red[512] + loss_extra[1];
    *out_loss = 0.25f * ls / ns;
  }
}

extern "C" void kernel_launch(void* const* d_in, const int* in_sizes, int n_in,
                              void* d_out, int out_size, void* d_ws, size_t ws_size,
                              hipStream_t stream) {
  (void)in_sizes; (void)n_in; (void)out_size; (void)ws_size;
  const float* x = (const float*)d_in[0];
  const float* emb = (const float*)d_in[1];

  float* out = (float*)d_out;
  float* qst = out;                   // 16777216
  float* out_loss = out + 16777216;   // 1
  float* out_idxf = out + 16777217;   // 65536
  float* out_perp = out + 16842753;   // 1

  float* ws = (float*)d_ws;
  float* xnorm = ws;                        // 65536
  float* enorm = ws + 65536;                // 1024
  int* idx = (int*)(ws + 66560);            // 65536
  float* counts = ws + 132096;              // 1024
  float* lpart = ws + 133120;               // 512
  float* npart = ws + 133632;               // 512
  float* loss_extra = ws + 134144;          // 2
  int* nflag = (int*)(ws + 134148);         // 1
  int* flist = (int*)(ws + 134160);         // 65536
  unsigned short* eimg = (unsigned short*)(ws + 199696);  // 1 MB (524288 ushort), 16B-aligned
  float* embT = ws + 461840;                // 1 MB (262144 floats)

  norms_init_kernel<<<4160, 256, 0, stream>>>(x, emb, xnorm, enorm, counts, nflag, loss_extra);
  eimg_kernel<<<512, 256, 0, stream>>>(emb, eimg, embT);
  score_kernel<<<512, 256, 0, stream>>>(x, emb, xnorm, enorm, eimg, idx, out_idxf,
                                        qst, counts, lpart, npart, nflag, flist);
  rescore_kernel<<<1024, 256, 0, stream>>>(x, emb, embT, xnorm, enorm, idx, out_idxf,
                                           qst, counts, loss_extra, nflag, flist);
  finalize_kernel<<<1, 256, 0, stream>>>(counts, lpart, npart, loss_extra, out_loss, out_perp);
}